// Round 1
// baseline (331.670 us; speedup 1.0000x reference)
//
#include <hip/hip_runtime.h>

// TimeConcater: new_x[b,p,d] = sum_l [bucket(ts[b,l])==p] * x[b,l,d]
// B=32, L=4096, D=256, P=32 buckets over np.linspace(0,1.001,33) edges.
// Output flat: new_x (32,32,256), then time_steps (32,4096).
//
// R9: invert the loop. Previous structures (R2-R8) all GATHERED rows by
// bucket -> scattered 1KB reads at ~32KB gaps -> pinned at 0.8-1.7 TB/s
// (DRAM page/activate-bound; "invariant to structure" because every
// structure kept the gather). Here x is read STRICTLY SEQUENTIALLY
// (the 6.3 TB/s pattern, m13) and rows are routed on-chip:
//   stream row -> ds_add_f32 into per-block LDS bucket accumulator
//   (transposed [p][j][64] layout => conflict-free LDS atomics)
//   -> one global unsafeAtomicAdd merge per acc element at block end.
// Output is zeroed with hipMemsetAsync (graph-capturable) before launch.

#define Bk 32
#define Lk 4096
#define Dk 256
#define Pk 32
#define NCHUNK 16
#define ROWS (Lk / NCHUNK)   // 256 rows per block, 256 KB of x
#define NTH 512              // 8 waves
#define NW 8

typedef float v4f __attribute__((ext_vector_type(4)));

__device__ __forceinline__ int bucket_of(float tv) {
    // Emulate np.linspace(0.0, 1.001, 33): edge(i) = float32((double)i * (1.001/32))
    const double step = 1.001 / 32.0;
    int p = (int)(tv * (float)(32.0 / 1.001));
    p = p < 0 ? 0 : (p > 31 ? 31 : p);
    while (p > 0 && tv < (float)((double)p * step)) --p;
    while (p < 31 && tv >= (float)((double)(p + 1) * step)) ++p;
    return p;
}

__global__ __launch_bounds__(NTH, 4) void tc_stream(
        const float* __restrict__ x,
        const float* __restrict__ ts,
        float* __restrict__ out,
        float* __restrict__ ts_out) {
    // acc[p][j][l] holds column 4*l + j of bucket p. Transposed so each
    // ds_add_f32 instruction hits 64 CONSECUTIVE floats (2 lanes/bank = free)
    // instead of stride-4 (8-way conflict).
    __shared__ float acc[Pk][4][64];      // 32 KB
    __shared__ int pbuf[ROWS];            // 1 KB

    const int c = blockIdx.x;
    const int b = blockIdx.y;
    const int t = threadIdx.x;
    const int w = t >> 6;
    const int lane = t & 63;
    const int base = c * ROWS;

    // Zero the accumulator (2048 v4f / 512 thr = 4 stores each).
    {
        v4f z = 0.f;
        v4f* a4 = (v4f*)&acc[0][0][0];
#pragma unroll
        for (int i = t; i < Pk * Dk / 4; i += NTH) a4[i] = z;
    }

    // Buckets for this chunk + ts passthrough (coalesced 1 KB).
    if (t < ROWS) {
        const size_t li = (size_t)b * Lk + base + t;
        const float tv = ts[li];
        ts_out[li] = tv;
        pbuf[t] = bucket_of(tv);
    }
    __syncthreads();

    // Sequential stream of this block's 256 KB slab: wave w owns rows
    // w, w+8, ... Each iteration: one 1KB dwordx4-NT row read (perfectly
    // coalesced, consecutive addresses block-wide) + 4 conflict-free
    // LDS float atomics. Unroll 4 => 4 KB in flight per wave.
    const float* xb = x + ((size_t)b * Lk + base) * Dk;
#pragma unroll 4
    for (int r = w; r < ROWS; r += NW) {
        const int p = pbuf[r];                       // wave-uniform broadcast
        const v4f v = __builtin_nontemporal_load(
            (const v4f*)(xb + (size_t)r * Dk + (lane << 2)));
        float* ap = &acc[p][0][lane];
        unsafeAtomicAdd(ap,       v.x);              // ds_add_f32, bank-free
        unsafeAtomicAdd(ap + 64,  v.y);
        unsafeAtomicAdd(ap + 128, v.z);
        unsafeAtomicAdd(ap + 192, v.w);
    }
    __syncthreads();

    // Merge into global out[b][p][col] (zeroed by memset). col=4l+j lives
    // at acc[p][col&3][col>>2]. 8192 atomics per block, coalesced.
    float* ob = out + (size_t)b * Pk * Dk;
#pragma unroll
    for (int i = t; i < Pk * Dk; i += NTH) {
        const int p = i >> 8;
        const int col = i & 255;
        unsafeAtomicAdd(ob + i, acc[p][col & 3][col >> 2]);
    }
}

extern "C" void kernel_launch(void* const* d_in, const int* in_sizes, int n_in,
                              void* d_out, int out_size, void* d_ws, size_t ws_size,
                              hipStream_t stream) {
    const float* x  = (const float*)d_in[0];
    const float* ts = (const float*)d_in[1];
    float* out = (float*)d_out;
    float* ts_out = out + (size_t)Bk * Pk * Dk;

    hipMemsetAsync(out, 0, (size_t)Bk * Pk * Dk * sizeof(float), stream);
    dim3 grid(NCHUNK, Bk);   // 512 blocks: (chunk, batch)
    tc_stream<<<grid, NTH, 0, stream>>>(x, ts, out, ts_out);
}

// Round 2
// 192.050 us; speedup vs baseline: 1.7270x; 1.7270x over previous
//
#include <hip/hip_runtime.h>

// TimeConcater: new_x[b,p,d] = sum_l [bucket(ts[b,l])==p] * x[b,l,d]
// B=32, L=4096, D=256, P=32 buckets over np.linspace(0,1.001,33) edges.
// Output flat: new_x (32,32,256), then time_steps (32,4096).
//
// R10: owner-writes, zero atomics. R9 post-mortem: sequential streaming +
// LDS accumulation via unsafeAtomicAdd ran 178us with VALUBusy=0.9%,
// VGPR=12 -> the flat-atomic lowering of unsafeAtomicAdd on an LDS
// pointer serialized the CU (131K flat atomics/CU at ~100-200cyc each
// matches 178us exactly). Loads were never the limiter once sequential.
// Fix: restructure so NO atomics exist at all:
//   block = (b, 32-col stripe), grid 32x8 = 256 = 1 block/CU.
//   Each block streams ALL 4096 rows of its stripe (line-dense 128B
//   pairs, disjoint cache lines across blocks), accumulating into
//   HALF-WAVE-PRIVATE LDS regions with plain ds_read/add/ds_write
//   (direct shared-array indexing -> guaranteed DS ops; regions private
//   -> no collisions; banks 2-way -> free). Epilogue reduces 16 regions
//   and plain-stores the block's exclusively-owned output stripe.
// Also removes the hipMemsetAsync node (the mysterious +153us in R9's
// graph): single dispatch, every output written exactly once.

#define Bk 32
#define Lk 4096
#define Dk 256
#define Pk 32
#define NSPLIT 8          // column splits
#define CS 32             // cols per split (NSPLIT*CS == Dk)
#define NTH 512           // 8 waves
#define NW 8

typedef float v4f __attribute__((ext_vector_type(4)));

__device__ __forceinline__ int bucket_of(float tv) {
    // Emulate np.linspace(0.0, 1.001, 33): edge(i) = float32((double)i * (1.001/32))
    const double step = 1.001 / 32.0;
    int p = (int)(tv * (float)(32.0 / 1.001));
    p = p < 0 ? 0 : (p > 31 ? 31 : p);
    while (p > 0 && tv < (float)((double)p * step)) --p;
    while (p < 31 && tv >= (float)((double)(p + 1) * step)) ++p;
    return p;
}

__global__ __launch_bounds__(NTH, 2) void tc_owner(
        const float* __restrict__ x,
        const float* __restrict__ ts,
        float* __restrict__ out,
        float* __restrict__ ts_out) {
    // Half-wave-private accumulators: region (w,h) is touched ONLY by
    // half-wave h of wave w. addr = (((w*2+h)*32 + p)*32 + c) dwords:
    // lane's bank = c = lane&31 always -> 2 lanes/bank (free, m136).
    __shared__ float wacc[NW][2][Pk][CS];   // 64 KB
    __shared__ unsigned char pbuf[Lk];      // 4 KB bucket per row

    const int cs = blockIdx.x;        // 0..7 column split
    const int b  = blockIdx.y;        // 0..31 batch
    const int t  = threadIdx.x;
    const int w  = t >> 6;            // wave 0..7
    const int lane = t & 63;
    const int h  = lane >> 5;         // half-wave 0/1
    const int c  = lane & 31;         // col within stripe

    // Zero accumulators (4096 v4f / 512 thr = 8 stores each).
    {
        v4f z = 0.f;
        v4f* az = (v4f*)&wacc[0][0][0][0];
#pragma unroll
        for (int i = t; i < NW * 2 * Pk * CS / 4; i += NTH) az[i] = z;
    }

    // Buckets for all rows of this batch (byte-packed), coalesced ts reads.
    const float* tsb = ts + (size_t)b * Lk;
#pragma unroll
    for (int j = t; j < Lk; j += NTH)
        pbuf[j] = (unsigned char)bucket_of(tsb[j]);

    // ts passthrough: this block owns rows [cs*512, cs*512+512).
    {
        const int j = cs * (Lk / NSPLIT) + t;   // Lk/NSPLIT == NTH
        ts_out[(size_t)b * Lk + j] = tsb[j];
    }
    __syncthreads();

    // Main stream: iteration i, wave w: rows i*16 + w*2 + {0,1}.
    // Lane reads x[b, row, cs*32 + c] (two 128B line-pairs per instr,
    // disjoint lines across blocks -> no redundant fetch), then RMWs its
    // private LDS cell. Plain DS ops; unroll 8 keeps 8 loads in flight.
    const float* xb = x + ((size_t)b * Lk) * Dk + cs * CS + c;
    const int rbase = (w << 1) + h;
#pragma unroll 8
    for (int i = 0; i < Lk / 16; ++i) {
        const int row = (i << 4) + rbase;
        const float v = __builtin_nontemporal_load(xb + (size_t)row * Dk);
        const int p = pbuf[row];
        wacc[w][h][p][c] += v;
    }
    __syncthreads();

    // Epilogue: out[b][p][cs*32+c2] = sum of the 16 private regions.
    // Block exclusively owns its (b, all p, 32-col) stripe -> plain store,
    // no memset needed, output written exactly once.
    float* ob = out + ((size_t)b * Pk) * Dk + cs * CS;
#pragma unroll
    for (int e = t; e < Pk * CS; e += NTH) {
        const int p = e >> 5;
        const int c2 = e & 31;
        float s = 0.f;
#pragma unroll
        for (int r = 0; r < NW * 2; ++r)
            s += wacc[r >> 1][r & 1][p][c2];
        ob[(size_t)p * Dk + c2] = s;
    }
}

extern "C" void kernel_launch(void* const* d_in, const int* in_sizes, int n_in,
                              void* d_out, int out_size, void* d_ws, size_t ws_size,
                              hipStream_t stream) {
    const float* x  = (const float*)d_in[0];
    const float* ts = (const float*)d_in[1];
    float* out = (float*)d_out;
    float* ts_out = out + (size_t)Bk * Pk * Dk;

    dim3 grid(NSPLIT, Bk);   // 256 blocks = 1 per CU; no memset, no atomics
    tc_owner<<<grid, NTH, 0, stream>>>(x, ts, out, ts_out);
}